// Round 3
// baseline (1289.706 us; speedup 1.0000x reference)
//
#include <hip/hip_runtime.h>

#define DD 128
#define NN 20000
#define NE 640000
#define EOFF (NN * DD)

typedef __attribute__((ext_vector_type(8))) short short8;
typedef __attribute__((ext_vector_type(4))) float float4v;

__device__ __forceinline__ short f2bf(float x) {
    union { float f; unsigned int u; } v; v.f = x;
    unsigned int u = v.u + 0x7FFFu + ((v.u >> 16) & 1u);  // RNE
    return (short)(u >> 16);
}

__device__ __forceinline__ short8 cvt8(float4v a, float4v b) {
    short8 r;
    r[0] = f2bf(a[0]); r[1] = f2bf(a[1]); r[2] = f2bf(a[2]); r[3] = f2bf(a[3]);
    r[4] = f2bf(b[0]); r[5] = f2bf(b[1]); r[6] = f2bf(b[2]); r[7] = f2bf(b[3]);
    return r;
}

// Pack W [128x128 f32, row-major K x N] -> bf16 fragment-friendly:
// Wpk[(kb*128 + c)*8 + j] = W[(kb*8+j)*128 + c]   (kb in [0,16), j in [0,8))
// Matrices in order: a, b, d, e, c
__global__ __launch_bounds__(256) void prep_pack(const float* __restrict__ Wa, const float* __restrict__ Wb,
                                                 const float* __restrict__ Wd, const float* __restrict__ We,
                                                 const float* __restrict__ Wc, short* __restrict__ Wpk) {
    int t = blockIdx.x * 256 + threadIdx.x;   // 0..10239
    if (t >= 5 * 2048) return;
    int m = t / 2048, pos = t % 2048;
    int kb = pos >> 7, c = pos & 127;
    const float* W = (m == 0) ? Wa : (m == 1) ? Wb : (m == 2) ? Wd : (m == 3) ? We : Wc;
    short8 r;
#pragma unroll
    for (int j = 0; j < 8; ++j) r[j] = f2bf(W[(kb * 8 + j) * DD + c]);
    *(short8*)&Wpk[m * 16384 + pos * 8] = r;
}

// Shared MFMA tile: 32 rows x 128 cols, K=128. rowbase points at row 0 of the tile.
// A-frag: lane reads rows (mf*16 + lr), k = ks*32 + lg*8 + j  (8 consecutive f32 -> bf16)
// B-frag: packed LDS read, contiguous 16B.
__device__ __forceinline__ void gemm_tile(const float* __restrict__ rowbase,
                                          const short* __restrict__ wl,
                                          int lg, int lr, float4v acc[2][8]) {
#pragma unroll
    for (int ks = 0; ks < 4; ++ks) {
        short8 af[2];
#pragma unroll
        for (int mf = 0; mf < 2; ++mf) {
            const float* p = rowbase + (mf * 16 + lr) * DD + ks * 32 + lg * 8;
            af[mf] = cvt8(*(const float4v*)p, *(const float4v*)(p + 4));
        }
#pragma unroll
        for (int nf = 0; nf < 8; ++nf) {
            short8 bfv = *(const short8*)&wl[((ks * 4 + lg) * DD + nf * 16 + lr) * 8];
            acc[0][nf] = __builtin_amdgcn_mfma_f32_16x16x32_bf16(af[0], bfv, acc[0][nf], 0, 0, 0);
            acc[1][nf] = __builtin_amdgcn_mfma_f32_16x16x32_bf16(af[1], bfv, acc[1][nf], 0, 0, 0);
        }
    }
}

// Node GEMMs: out[m] = X @ W[m] + b[m], m selects {a,b,d,e} via blockIdx.y.
__global__ __launch_bounds__(256) void node_gemm(const float* __restrict__ X, const short* __restrict__ Wpk,
                                                 const float* __restrict__ ba, const float* __restrict__ bb,
                                                 const float* __restrict__ bd, const float* __restrict__ be,
                                                 float* __restrict__ ws_out) {
    __shared__ short wl[16384];
    int tid = threadIdx.x;
    int m = blockIdx.y;
    const short* wsrc = Wpk + m * 16384;
    for (int i = tid; i < 2048; i += 256) ((short8*)wl)[i] = ((const short8*)wsrc)[i];
    __syncthreads();
    int wv = tid >> 6, lane = tid & 63, lg = lane >> 4, lr = lane & 15;
    int row0 = blockIdx.x * 128 + wv * 32;
    float4v acc[2][8];
#pragma unroll
    for (int a = 0; a < 2; ++a)
#pragma unroll
        for (int b = 0; b < 8; ++b) acc[a][b] = (float4v)(0.f);
#pragma unroll
    for (int ks = 0; ks < 4; ++ks) {
        short8 af[2];
#pragma unroll
        for (int mf = 0; mf < 2; ++mf) {
            int r = row0 + mf * 16 + lr;
            if (r > NN - 1) r = NN - 1;           // clamp (values discarded via store guard)
            const float* p = X + (size_t)r * DD + ks * 32 + lg * 8;
            af[mf] = cvt8(*(const float4v*)p, *(const float4v*)(p + 4));
        }
#pragma unroll
        for (int nf = 0; nf < 8; ++nf) {
            short8 bfv = *(const short8*)&wl[((ks * 4 + lg) * DD + nf * 16 + lr) * 8];
            acc[0][nf] = __builtin_amdgcn_mfma_f32_16x16x32_bf16(af[0], bfv, acc[0][nf], 0, 0, 0);
            acc[1][nf] = __builtin_amdgcn_mfma_f32_16x16x32_bf16(af[1], bfv, acc[1][nf], 0, 0, 0);
        }
    }
    const float* bias = (m == 0) ? ba : (m == 1) ? bb : (m == 2) ? bd : be;
    float* out = ws_out + (size_t)m * (NN * DD);
#pragma unroll
    for (int nf = 0; nf < 8; ++nf) {
        int c = nf * 16 + lr;
        float bv = bias[c];
#pragma unroll
        for (int mf = 0; mf < 2; ++mf)
#pragma unroll
            for (int r = 0; r < 4; ++r) {
                int row = row0 + mf * 16 + lg * 4 + r;
                if (row < NN) out[(size_t)row * DD + c] = acc[mf][nf][r] + bv;
            }
    }
}

// Edge pass 1: e = E_X@Wc + bc + DX[src] + EX[dst]; sigma; segment sums (wave = one node);
// Hpre = (AX + num/(den+eps))*snorm_n; per-block BN partial stats for e*snorm_e and Hpre.
__global__ __launch_bounds__(256) void edge1(
    const float* __restrict__ EXm, const float* __restrict__ snn, const float* __restrict__ sne,
    const int* __restrict__ src, const short* __restrict__ WpkC, const float* __restrict__ bc,
    const float* __restrict__ AX, const float* __restrict__ BX,
    const float* __restrict__ DXn, const float* __restrict__ EXn,
    const float* __restrict__ epsp, float* __restrict__ Hpre, float* __restrict__ partials) {
    __shared__ short wl[16384];
    __shared__ float st[512];
    int tid = threadIdx.x;
    st[tid] = 0.f; st[tid + 256] = 0.f;
    for (int i = tid; i < 2048; i += 256) ((short8*)wl)[i] = ((const short8*)WpkC)[i];
    __syncthreads();
    int wv = tid >> 6, lane = tid & 63, lg = lane >> 4, lr = lane & 15;
    int node = blockIdx.x * 4 + wv;
    int ebase = node * 32;
    float4v acc[2][8];
#pragma unroll
    for (int a = 0; a < 2; ++a)
#pragma unroll
        for (int b = 0; b < 8; ++b) acc[a][b] = (float4v)(0.f);
    gemm_tile(EXm + (size_t)ebase * DD, wl, lg, lr, acc);

    int sidx[2][4]; float sn[2][4];
#pragma unroll
    for (int mf = 0; mf < 2; ++mf)
#pragma unroll
        for (int r = 0; r < 4; ++r) {
            int er = ebase + mf * 16 + lg * 4 + r;
            sidx[mf][r] = src[er];
            sn[mf][r] = sne[er];
        }
    float epsv = epsp[0];
    float snv = snn[node];
#pragma unroll
    for (int nf = 0; nf < 8; ++nf) {
        int c = nf * 16 + lr;
        float bcv = bc[c];
        float exv = EXn[(size_t)node * DD + c];   // dst is wave-uniform: dst[er] == node
        float nu = 0.f, de = 0.f, es = 0.f, eq = 0.f;
#pragma unroll
        for (int mf = 0; mf < 2; ++mf)
#pragma unroll
            for (int r = 0; r < 4; ++r) {
                float e = acc[mf][nf][r] + bcv + DXn[(size_t)sidx[mf][r] * DD + c] + exv;
                float sg = 1.f / (1.f + __expf(-e));
                nu += sg * BX[(size_t)sidx[mf][r] * DD + c];
                de += sg;
                float z = e * sn[mf][r];
                es += z; eq += z * z;
            }
        nu += __shfl_xor(nu, 16); nu += __shfl_xor(nu, 32);
        de += __shfl_xor(de, 16); de += __shfl_xor(de, 32);
        es += __shfl_xor(es, 16); es += __shfl_xor(es, 32);
        eq += __shfl_xor(eq, 16); eq += __shfl_xor(eq, 32);
        if (lg == 0) {
            float hv = (AX[(size_t)node * DD + c] + nu / (de + epsv)) * snv;
            Hpre[(size_t)node * DD + c] = hv;
            atomicAdd(&st[c], es);
            atomicAdd(&st[c + 128], eq);
            atomicAdd(&st[c + 256], hv);
            atomicAdd(&st[c + 384], hv * hv);
        }
    }
    __syncthreads();
    partials[(size_t)blockIdx.x * 512 + tid] = st[tid];
    partials[(size_t)blockIdx.x * 512 + 256 + tid] = st[tid + 256];
}

// Reduce per-block partials -> affine BN coefficients A,B per column.
// stats layout: [0,128)=A_e [128,256)=B_e [256,384)=A_h [384,512)=B_h
__global__ __launch_bounds__(512) void stats_reduce(const float* __restrict__ partials,
                                                    const float* __restrict__ gh, const float* __restrict__ bh,
                                                    const float* __restrict__ ge, const float* __restrict__ bev,
                                                    float* __restrict__ statsOut) {
    __shared__ float ls[512], lq[512];
    int tid = threadIdx.x;
    int j = tid & 127, sl = tid >> 7;
    int base = blockIdx.x * 256;   // 0: e-stats, 256: h-stats
    float s = 0.f, q = 0.f;
    for (int b = sl; b < 5000; b += 4) {
        s += partials[(size_t)b * 512 + base + j];
        q += partials[(size_t)b * 512 + base + 128 + j];
    }
    ls[tid] = s; lq[tid] = q;
    __syncthreads();
    if (sl == 0) {
        s = ls[j] + ls[128 + j] + ls[256 + j] + ls[384 + j];
        q = lq[j] + lq[128 + j] + lq[256 + j] + lq[384 + j];
        float invN = (blockIdx.x == 0) ? (1.f / 640000.f) : (1.f / 20000.f);
        float mean = s * invN;
        float var = q * invN - mean * mean;
        const float* g = (blockIdx.x == 0) ? ge : gh;
        const float* bt = (blockIdx.x == 0) ? bev : bh;
        float A = g[j] * rsqrtf(var + 1e-5f);
        float B = bt[j] - mean * A;
        statsOut[base + j] = A;
        statsOut[base + 128 + j] = B;
    }
}

// H = X + relu(Hpre * A_h + B_h)
__global__ __launch_bounds__(256) void node_out(const float* __restrict__ Hpre, const float* __restrict__ X,
                                                const float* __restrict__ stats, float* __restrict__ out) {
    int i = blockIdx.x * 256 + threadIdx.x;   // < 640000 float4s
    float4v hp = ((const float4v*)Hpre)[i];
    float4v xx = ((const float4v*)X)[i];
    int cb = i & 31;
    float4v Ah = ((const float4v*)(stats + 256))[cb];
    float4v Bh = ((const float4v*)(stats + 384))[cb];
    float4v o;
#pragma unroll
    for (int k = 0; k < 4; ++k) o[k] = xx[k] + fmaxf(hp[k] * Ah[k] + Bh[k], 0.f);
    ((float4v*)out)[i] = o;
}

// Edge pass 2: recompute e, apply BN affine + relu + residual, write E_out.
__global__ __launch_bounds__(256) void edge2(
    const float* __restrict__ EXm, const float* __restrict__ sne,
    const int* __restrict__ src, const short* __restrict__ WpkC, const float* __restrict__ bc,
    const float* __restrict__ DXn, const float* __restrict__ EXn,
    const float* __restrict__ stats, float* __restrict__ out) {
    __shared__ short wl[16384];
    int tid = threadIdx.x;
    for (int i = tid; i < 2048; i += 256) ((short8*)wl)[i] = ((const short8*)WpkC)[i];
    __syncthreads();
    int wv = tid >> 6, lane = tid & 63, lg = lane >> 4, lr = lane & 15;
    int node = blockIdx.x * 4 + wv;
    int ebase = node * 32;
    float4v acc[2][8];
#pragma unroll
    for (int a = 0; a < 2; ++a)
#pragma unroll
        for (int b = 0; b < 8; ++b) acc[a][b] = (float4v)(0.f);
    gemm_tile(EXm + (size_t)ebase * DD, wl, lg, lr, acc);

    int sidx[2][4]; float sn[2][4];
#pragma unroll
    for (int mf = 0; mf < 2; ++mf)
#pragma unroll
        for (int r = 0; r < 4; ++r) {
            int er = ebase + mf * 16 + lg * 4 + r;
            sidx[mf][r] = src[er];
            sn[mf][r] = sne[er];
        }
#pragma unroll
    for (int nf = 0; nf < 8; ++nf) {
        int c = nf * 16 + lr;
        float bcv = bc[c];
        float exv = EXn[(size_t)node * DD + c];
        float Ae = stats[c], Be = stats[c + 128];
#pragma unroll
        for (int mf = 0; mf < 2; ++mf)
#pragma unroll
            for (int r = 0; r < 4; ++r) {
                int er = ebase + mf * 16 + lg * 4 + r;
                float e = acc[mf][nf][r] + bcv + DXn[(size_t)sidx[mf][r] * DD + c] + exv;
                float z = e * sn[mf][r];
                out[EOFF + (size_t)er * DD + c] = EXm[(size_t)er * DD + c] + fmaxf(z * Ae + Be, 0.f);
            }
    }
}

extern "C" void kernel_launch(void* const* d_in, const int* in_sizes, int n_in,
                              void* d_out, int out_size, void* d_ws, size_t ws_size,
                              hipStream_t stream) {
    (void)in_sizes; (void)n_in; (void)out_size; (void)ws_size;
    const float* X   = (const float*)d_in[0];
    const float* EXm = (const float*)d_in[1];
    const float* snn = (const float*)d_in[2];
    const float* sne = (const float*)d_in[3];
    const int*   src = (const int*)d_in[4];
    // d_in[5] = dst: implied by edge index (er/32), unused
    const float* Wa = (const float*)d_in[6];
    const float* ba = (const float*)d_in[7];
    const float* Wb = (const float*)d_in[8];
    const float* bb = (const float*)d_in[9];
    const float* Wc = (const float*)d_in[10];
    const float* bc = (const float*)d_in[11];
    const float* Wd = (const float*)d_in[12];
    const float* bd = (const float*)d_in[13];
    const float* We = (const float*)d_in[14];
    const float* be = (const float*)d_in[15];
    const float* gh = (const float*)d_in[16];
    const float* bh = (const float*)d_in[17];
    const float* ge = (const float*)d_in[18];
    const float* bev = (const float*)d_in[19];
    const float* eps = (const float*)d_in[20];
    float* out = (float*)d_out;

    char* wsb = (char*)d_ws;
    float* AXp  = (float*)wsb;                              // 4 node GEMM outputs, contiguous [a,b,d,e]
    float* BXp  = AXp + (size_t)NN * DD;
    float* DXp  = BXp + (size_t)NN * DD;
    float* EXp  = DXp + (size_t)NN * DD;
    float* Hpre = EXp + (size_t)NN * DD;
    short* Wpk  = (short*)(wsb + (size_t)5 * NN * DD * 4);  // 5 * 32 KB packed bf16 weights
    float* partials = (float*)(wsb + (size_t)5 * NN * DD * 4 + 5 * 16384 * 2);  // 5000*512 f32
    float* stats = partials + (size_t)5000 * 512;           // 512 f32

    hipLaunchKernelGGL(prep_pack, dim3(40), dim3(256), 0, stream, Wa, Wb, Wd, We, Wc, Wpk);
    hipLaunchKernelGGL(node_gemm, dim3(157, 4), dim3(256), 0, stream, X, Wpk, ba, bb, bd, be, AXp);
    hipLaunchKernelGGL(edge1, dim3(5000), dim3(256), 0, stream,
                       EXm, snn, sne, src, Wpk + 4 * 16384, bc, AXp, BXp, DXp, EXp, eps, Hpre, partials);
    hipLaunchKernelGGL(stats_reduce, dim3(2), dim3(512), 0, stream, partials, gh, bh, ge, bev, stats);
    hipLaunchKernelGGL(node_out, dim3(2500), dim3(256), 0, stream, Hpre, X, stats, out);
    hipLaunchKernelGGL(edge2, dim3(5000), dim3(256), 0, stream,
                       EXm, sne, src, Wpk + 4 * 16384, bc, DXp, EXp, stats, out);
}